// Round 7
// baseline (152.046 us; speedup 1.0000x reference)
//
#include <hip/hip_runtime.h>

typedef unsigned int uint;
typedef unsigned short ushort;
typedef __attribute__((ext_vector_type(8))) short bf16x8;
typedef __attribute__((ext_vector_type(4))) short bf16x4;
typedef __attribute__((ext_vector_type(4))) float f32x4;

namespace {
constexpr int kS = 2048;
constexpr int kD = 512;
constexpr int kH = 8;
constexpr int kBand = 16;

// Workspace offsets (ushort units). Apk eliminated (A self-staged in gemm).
constexpr size_t kQpk = 0;                    // 32 bh x 128 g x 2 kc x 512
constexpr size_t kKpk = 4194304;              // 32 bh x 130 g x 2 kc x 512
constexpr size_t kVpk = kKpk + 4259840;       // 32 bh x 65 gg x 4 nt x 512
constexpr size_t kBpk = kVpk + 4259840;       // 4 z x 8 c x 16 it x 2048
}  // namespace

static __device__ __forceinline__ ushort f2bf(float f) {
  uint u = __builtin_bit_cast(uint, f);
  u = (u + 0x7fffu + ((u >> 16) & 1u)) >> 16;  // RNE
  return (ushort)u;
}

// 8 fp32 -> bf16x8 via v_cvt_pk_bf16_f32 (RNE; bit-identical to f2bf).
static __device__ __forceinline__ bf16x8 cvt8(f32x4 lo, f32x4 hi) {
  uint4 r;
  asm("v_cvt_pk_bf16_f32 %0, %1, %2" : "=v"(r.x) : "v"(lo[0]), "v"(lo[1]));
  asm("v_cvt_pk_bf16_f32 %0, %1, %2" : "=v"(r.y) : "v"(lo[2]), "v"(lo[3]));
  asm("v_cvt_pk_bf16_f32 %0, %1, %2" : "=v"(r.z) : "v"(hi[0]), "v"(hi[1]));
  asm("v_cvt_pk_bf16_f32 %0, %1, %2" : "=v"(r.w) : "v"(hi[2]), "v"(hi[3]));
  return __builtin_bit_cast(bf16x8, r);
}

// 4 fp32 -> bf16x4 (8B) for the b64 fragment-stage writes.
static __device__ __forceinline__ bf16x4 cvt4(f32x4 x) {
  uint2 r;
  asm("v_cvt_pk_bf16_f32 %0, %1, %2" : "=v"(r.x) : "v"(x[0]), "v"(x[1]));
  asm("v_cvt_pk_bf16_f32 %0, %1, %2" : "=v"(r.y) : "v"(x[2]), "v"(x[3]));
  return __builtin_bit_cast(bf16x4, r);
}

// ---------------------------------------------------------------------------
// prep_all: [0,256): weights -> Bpk packed. [256,320): Vpk pad zero-fill.
// (A packing removed: gemm_qkv self-stages fp32 A.)
// ---------------------------------------------------------------------------
__global__ __launch_bounds__(256) void prep_all(
    const float* __restrict__ wq, const float* __restrict__ wk,
    const float* __restrict__ wv, const float* __restrict__ wo,
    ushort* __restrict__ ws) {
  __shared__ float Ws[64][65];
  const int blk = blockIdx.x, tid = threadIdx.x;
  if (blk >= 256) {  // ---- Vpk pad zero-fill ----
    const int idx = blk - 256;  // 0..63
    const int bh = idx >> 1, gg = (idx & 1) * 64;
    ushort* p = ws + kVpk + ((size_t)(bh * 65 + gg) * 4) * 512 + tid * 8;
    *(uint4*)p = (uint4){0, 0, 0, 0};
    return;
  }
  // ---- weight packing ----
  const int w = blk;  // 0..255
  const int z = w >> 6;
  const float* W = z == 0 ? wq : (z == 1 ? wk : (z == 2 ? wv : wo));
  const int kt = ((w >> 3) & 7) * 64, nt = (w & 7) * 64;
  const int r = tid >> 2, c0 = (tid & 3) * 16;
#pragma unroll
  for (int i = 0; i < 4; ++i) {
    const float4 x =
        *(const float4*)(W + (size_t)(kt + r) * kD + nt + c0 + i * 4);
    Ws[r][c0 + i * 4 + 0] = x.x;
    Ws[r][c0 + i * 4 + 1] = x.y;
    Ws[r][c0 + i * 4 + 2] = x.z;
    Ws[r][c0 + i * 4 + 3] = x.w;
  }
  __syncthreads();
  const int nl = tid >> 2, k0 = (tid & 3) * 16;
  alignas(16) ushort tmp[16];
#pragma unroll
  for (int i = 0; i < 16; ++i) tmp[i] = f2bf(Ws[k0 + i][nl]);
  const int ng = nt + nl, kg = kt + k0;
  const int c = ng >> 6, sub = (ng >> 4) & 3, l = ng & 15;
  const int it = kg >> 5, q0 = (kg >> 3) & 3;  // q0 in {0,2}
  ushort* base = ws + kBpk + ((size_t)(z * 8 + c) * 16 + it) * 2048 +
                 (sub * 64 + l) * 8;
  *(uint4*)(base + q0 * 128) = *(const uint4*)&tmp[0];
  *(uint4*)(base + (q0 + 1) * 128) = *(const uint4*)&tmp[8];
}

// ---------------------------------------------------------------------------
// QKV GEMM, barrier-free with per-wave A self-staging. One wave per 64x64
// tile. Per K-step the wave stages its 64x32 fp32 A slab: 8 global f32x4
// loads (each instr = 8 rows x 128B full lines), cvt_pk -> b64 writes into a
// double-buffered fragment-layout LDS stage (4KB). Fragment ds_read_b128s
// read contiguous 1KB (conflict-free). Sync is wave-local lgkmcnt(0) ONLY —
// no s_barrier anywhere. B direct from L2-resident packed Bpk (2-deep).
// Stage layout (ushort idx): ((k>>3)*16 + (r&15))*8 + (k&7) + (r>>4)*512.
// Epilogue (identical to r6) packs Q/K/V for attn.
// ---------------------------------------------------------------------------
__global__ __launch_bounds__(64) void gemm_qkv(
    const float* __restrict__ q, const float* __restrict__ k,
    const float* __restrict__ v, const ushort* __restrict__ ws_c,
    ushort* __restrict__ ws, const float* __restrict__ bq,
    const float* __restrict__ bk, const float* __restrict__ bv) {
  __shared__ alignas(16) ushort smem[4608];  // [0,4096): A dbuf; then Tl reuse

  const int lane = threadIdx.x, l15 = lane & 15, qd = lane >> 4;
  const int lin = blockIdx.x;
  const int xcd = lin & 7, j = lin >> 3;
  const int ct = j & 7;
  const int rtl = xcd + 8 * (j >> 3);  // 0..383
  const int mode = rtl >> 7, rt = rtl & 127;
  const int row0 = rt * 64;

  const float* Ab = mode == 0 ? q : (mode == 1 ? k : v);
  const float* bias = mode == 0 ? bq : (mode == 1 ? bk : bv);
  const ushort* pb =
      ws_c + kBpk + ((size_t)(mode * 8 + ct) * 16) * 2048 + lane * 8;

  // A staging map: lane (g = lane>>3, kc = lane&7); load i covers row i*8+g,
  // floats kc*4..kc*4+3 (lanes of a row = 128B contiguous, full lines).
  const int g = lane >> 3, kc = lane & 7;
  const float* pAld[8];
#pragma unroll
  for (int i = 0; i < 8; ++i)
    pAld[i] = Ab + (size_t)(row0 + i * 8 + g) * kD + kc * 4;
  // b64 write dest for load i: wbase + (i&1)*64 + (i>>1)*512 (ushorts).
  const uint wbase = (uint)((kc >> 1) * 128 + g * 8 + (kc & 1) * 4);

  f32x4 acc[4][4];
#pragma unroll
  for (int mi = 0; mi < 4; ++mi)
#pragma unroll
    for (int ni = 0; ni < 4; ++ni) acc[mi][ni] = (f32x4)(0.f);

  f32x4 Ld[8];
  bf16x8 Bf[3][4];

  // Prologue: stage0 load+write; stage1 loads held in Ld; B slots 0,1.
#pragma unroll
  for (int i = 0; i < 8; ++i) Ld[i] = *(const f32x4*)(pAld[i]);
#pragma unroll
  for (int i = 0; i < 8; ++i)
    *(bf16x4*)&smem[wbase + (i & 1) * 64 + (i >> 1) * 512] = cvt4(Ld[i]);
#pragma unroll
  for (int i = 0; i < 8; ++i) Ld[i] = *(const f32x4*)(pAld[i] + 32);
#pragma unroll
  for (int x = 0; x < 4; ++x) {
    Bf[0][x] = *(const bf16x8*)(pb + x * 512);
    Bf[1][x] = *(const bf16x8*)(pb + 2048 + x * 512);
  }

#pragma unroll
  for (int it = 0; it < 16; ++it) {
    // Writes of stage (it) finished? (issued last iter) — wave-local drain.
    asm volatile("s_waitcnt lgkmcnt(0)" ::: "memory");
    __builtin_amdgcn_sched_barrier(0);
    bf16x8 af[4];
    const uint sb = (uint)(it & 1) * 2048;
#pragma unroll
    for (int mi = 0; mi < 4; ++mi)
      af[mi] = *(const bf16x8*)&smem[sb + mi * 512 + (qd * 16 + l15) * 8];
    if (it < 15) {  // write stage it+1 from Ld (compiler waits vmcnt on Ld)
      const uint sb1 = (uint)((it + 1) & 1) * 2048;
#pragma unroll
      for (int i = 0; i < 8; ++i)
        *(bf16x4*)&smem[sb1 + wbase + (i & 1) * 64 + (i >> 1) * 512] =
            cvt4(Ld[i]);
    }
    if (it < 14) {  // refill Ld for stage it+2 (<=1920B imm offsets)
#pragma unroll
      for (int i = 0; i < 8; ++i)
        Ld[i] = *(const f32x4*)(pAld[i] + (it + 2) * 32);
#pragma unroll
      for (int x = 0; x < 4; ++x)
        Bf[(it + 2) % 3][x] =
            *(const bf16x8*)(pb + (size_t)(it + 2) * 2048 + x * 512);
    }
    const int s = it % 3;
#pragma unroll
    for (int mi = 0; mi < 4; ++mi)
#pragma unroll
      for (int ni = 0; ni < 4; ++ni)
        acc[mi][ni] = __builtin_amdgcn_mfma_f32_16x16x32_bf16(
            af[mi], Bf[s][ni], acc[mi][ni], 0, 0, 0);
  }
  asm volatile("s_waitcnt lgkmcnt(0)" ::: "memory");  // drain before Tl reuse
  __builtin_amdgcn_sched_barrier(0);

  float bcol[4];
#pragma unroll
  for (int ni = 0; ni < 4; ++ni) bcol[ni] = bias[ct * 64 + ni * 16 + l15];

  ushort* Tl = smem;
  const int bh = (row0 >> 11) * kH + ct;  // b*8 + h (head == col-tile)
  if (mode <= 1) {  // transpose to [token_local][dlocal], store packed Q/K
#pragma unroll
    for (int mi = 0; mi < 4; ++mi)
#pragma unroll
      for (int ni = 0; ni < 4; ++ni)
#pragma unroll
        for (int r = 0; r < 4; ++r)
          Tl[(mi * 16 + qd * 4 + r) * 72 + ni * 16 + l15] =
              f2bf(acc[mi][ni][r] + bcol[ni]);
    asm volatile("s_waitcnt lgkmcnt(0)" ::: "memory");
    const int s = (row0 & (kS - 1)) + lane;  // in-batch position
    const int gq = s >> 4;
    const ushort* Trow = &Tl[lane * 72];
    ushort* base =
        (mode == 0)
            ? ws + kQpk + ((size_t)(bh * 128 + gq) * 2) * 512 + (s & 15) * 8
            : ws + kKpk + ((size_t)(bh * 130 + gq + 1) * 2) * 512 +
                  (s & 15) * 8;
#pragma unroll
    for (int cc = 0; cc < 8; ++cc)
      *(uint4*)(base + (cc >> 2) * 512 + (cc & 3) * 128) =
          *(const uint4*)&Trow[cc * 8];
  } else {  // mode 2: transpose to [dlocal][token_local], store packed V
#pragma unroll
    for (int mi = 0; mi < 4; ++mi)
#pragma unroll
      for (int ni = 0; ni < 4; ++ni)
#pragma unroll
        for (int r = 0; r < 4; ++r)
          Tl[(ni * 16 + l15) * 72 + mi * 16 + qd * 4 + r] =
              f2bf(acc[mi][ni][r] + bcol[ni]);
    asm volatile("s_waitcnt lgkmcnt(0)" ::: "memory");
    const int nt = lane >> 4, l15v = lane & 15;
    const int sb2 = (row0 & (kS - 1)) + 16;
    const ushort* Trow = &Tl[lane * 72];
#pragma unroll
    for (int cc = 0; cc < 8; ++cc) {
      const int sc = sb2 + cc * 8;
      const int gg = sc >> 5, khc = (sc >> 3) & 3;
      ushort* dst = ws + kVpk + ((size_t)(bh * 65 + gg) * 4 + nt) * 512 +
                    khc * 128 + l15v * 8;
      *(uint4*)dst = *(const uint4*)&Trow[cc * 8];
    }
  }
}

// ---------------------------------------------------------------------------
// FUSED attention + out-projection (unchanged from r6). Block = 512 threads
// = 8 waves = 8 heads of one (b, 32-query tile). grid (64, 4).
// ---------------------------------------------------------------------------
__global__ __launch_bounds__(512) void attn_out(
    const ushort* __restrict__ ws_c, const float* __restrict__ bo,
    float* __restrict__ outp) {
  __shared__ alignas(16) ushort Pl[8 * 32 * 72];  // per-wave slices

  const int tid = threadIdx.x;
  const int w = tid >> 6, lane = tid & 63, l15 = lane & 15, qd = lane >> 4;
  const int b = blockIdx.y;
  const int q0 = blockIdx.x * 32;
  const int bh = b * kH + w;  // wave == head
  ushort* Plw = &Pl[w * 2304];

  const ushort* Qpk = ws_c + kQpk;
  const ushort* Kpk = ws_c + kKpk;
  const ushort* Vpk = ws_c + kVpk;

  // ---- attention phase ----
  bf16x8 qf[2][2], kf[4][2];
#pragma unroll
  for (int mi = 0; mi < 2; ++mi)
#pragma unroll
    for (int kc = 0; kc < 2; ++kc)
      qf[mi][kc] = *(const bf16x8*)&Qpk[((size_t)(bh * 128 + (q0 >> 4) + mi) *
                                            2 + kc) * 512 + lane * 8];
#pragma unroll
  for (int ni = 0; ni < 4; ++ni)
#pragma unroll
    for (int kc = 0; kc < 2; ++kc)
      kf[ni][kc] = *(const bf16x8*)&Kpk[((size_t)(bh * 130 + (q0 >> 4) + ni) *
                                            2 + kc) * 512 + lane * 8];

  f32x4 S[2][4];
#pragma unroll
  for (int mi = 0; mi < 2; ++mi)
#pragma unroll
    for (int ni = 0; ni < 4; ++ni) S[mi][ni] = (f32x4)(0.f);
#pragma unroll
  for (int mi = 0; mi < 2; ++mi)
#pragma unroll
    for (int ni = 0; ni < 4; ++ni)
#pragma unroll
      for (int kc = 0; kc < 2; ++kc)
        S[mi][ni] = __builtin_amdgcn_mfma_f32_16x16x32_bf16(
            qf[mi][kc], kf[ni][kc], S[mi][ni], 0, 0, 0);

#pragma unroll
  for (int mi = 0; mi < 2; ++mi)
#pragma unroll
    for (int ni = 0; ni < 4; ++ni)
#pragma unroll
      for (int r = 0; r < 4; ++r) {
        const int q_local = mi * 16 + qd * 4 + r;
        const int key_local = ni * 16 + l15;
        const int key = q0 - kBand + key_local;
        const int dlt = key_local - q_local;
        const bool ok = (dlt >= 0) && (dlt <= 32) && (key >= 0) && (key < kS);
        S[mi][ni][r] = ok ? S[mi][ni][r] * 0.125f : -3.0e38f;
      }

  float inv[2][4];
#pragma unroll
  for (int mi = 0; mi < 2; ++mi)
#pragma unroll
    for (int r = 0; r < 4; ++r) {
      float m = S[mi][0][r];
#pragma unroll
      for (int ni = 1; ni < 4; ++ni) m = fmaxf(m, S[mi][ni][r]);
      m = fmaxf(m, __shfl_xor(m, 1));
      m = fmaxf(m, __shfl_xor(m, 2));
      m = fmaxf(m, __shfl_xor(m, 4));
      m = fmaxf(m, __shfl_xor(m, 8));
      float s = 0.f;
#pragma unroll
      for (int ni = 0; ni < 4; ++ni) {
        const float e = __expf(S[mi][ni][r] - m);
        S[mi][ni][r] = e;
        s += e;
      }
      s += __shfl_xor(s, 1);
      s += __shfl_xor(s, 2);
      s += __shfl_xor(s, 4);
      s += __shfl_xor(s, 8);
      inv[mi][r] = 1.f / s;
    }

  // P -> own Pl slice (C-layout scatter, stride 72), read back in A-layout.
#pragma unroll
  for (int mi = 0; mi < 2; ++mi)
#pragma unroll
    for (int ni = 0; ni < 4; ++ni)
#pragma unroll
      for (int r = 0; r < 4; ++r)
        Plw[(mi * 16 + qd * 4 + r) * 72 + ni * 16 + l15] = f2bf(S[mi][ni][r]);
  asm volatile("s_waitcnt lgkmcnt(0)" ::: "memory");  // wave-local RAW

  f32x4 O[2][4];
#pragma unroll
  for (int mi = 0; mi < 2; ++mi)
#pragma unroll
    for (int nt = 0; nt < 4; ++nt) O[mi][nt] = (f32x4)(0.f);

#pragma unroll
  for (int kc = 0; kc < 2; ++kc) {
    bf16x8 pf[2], vfr[4];
#pragma unroll
    for (int mi = 0; mi < 2; ++mi)
      pf[mi] = *(const bf16x8*)&Plw[(mi * 16 + l15) * 72 + kc * 32 + qd * 8];
#pragma unroll
    for (int nt = 0; nt < 4; ++nt)
      vfr[nt] = *(const bf16x8*)&Vpk[((size_t)(bh * 65 + (q0 >> 5) + kc) * 4 +
                                       nt) * 512 + lane * 8];
#pragma unroll
    for (int mi = 0; mi < 2; ++mi)
#pragma unroll
      for (int nt = 0; nt < 4; ++nt)
        O[mi][nt] = __builtin_amdgcn_mfma_f32_16x16x32_bf16(pf[mi], vfr[nt],
                                                            O[mi][nt], 0, 0, 0);
  }

  // O (scaled) -> own Pl slice as [token_local][d_local], stride 72.
#pragma unroll
  for (int mi = 0; mi < 2; ++mi)
#pragma unroll
    for (int nt = 0; nt < 4; ++nt)
#pragma unroll
      for (int r = 0; r < 4; ++r)
        Plw[(mi * 16 + qd * 4 + r) * 72 + nt * 16 + l15] =
            f2bf(O[mi][nt][r] * inv[mi][r]);

  __syncthreads();  // all 8 heads' O visible to all waves

  // ---- out-projection phase: wave w computes cols [w*64, w*64+64) ----
  const ushort* pb =
      ws_c + kBpk + ((size_t)(3 * 8 + w) * 16) * 2048 + lane * 8;

  f32x4 acc[2][4];
#pragma unroll
  for (int mi = 0; mi < 2; ++mi)
#pragma unroll
    for (int ni = 0; ni < 4; ++ni) acc[mi][ni] = (f32x4)(0.f);

  bf16x8 Bf[2][4];
#pragma unroll
  for (int x = 0; x < 4; ++x) Bf[0][x] = *(const bf16x8*)(pb + x * 512);
#pragma unroll
  for (int it = 0; it < 16; ++it) {
    if (it < 15) {
#pragma unroll
      for (int x = 0; x < 4; ++x)
        Bf[(it + 1) & 1][x] =
            *(const bf16x8*)(pb + (size_t)(it + 1) * 2048 + x * 512);
    }
    bf16x8 af[2];
#pragma unroll
    for (int mi = 0; mi < 2; ++mi)
      af[mi] = *(const bf16x8*)&Pl[(it >> 1) * 2304 + (mi * 16 + l15) * 72 +
                                   (it & 1) * 32 + qd * 8];
#pragma unroll
    for (int mi = 0; mi < 2; ++mi)
#pragma unroll
      for (int ni = 0; ni < 4; ++ni)
        acc[mi][ni] = __builtin_amdgcn_mfma_f32_16x16x32_bf16(
            af[mi], Bf[it & 1][ni], acc[mi][ni], 0, 0, 0);
  }

#pragma unroll
  for (int ni = 0; ni < 4; ++ni) {
    const int colg = w * 64 + ni * 16 + l15;
    const float bc = bo[colg];
#pragma unroll
    for (int mi = 0; mi < 2; ++mi)
#pragma unroll
      for (int r = 0; r < 4; ++r) {
        const int token = b * kS + q0 + mi * 16 + qd * 4 + r;
        outp[(size_t)token * kD + colg] = acc[mi][ni][r] + bc;
      }
  }
}

extern "C" void kernel_launch(void* const* d_in, const int* in_sizes, int n_in,
                              void* d_out, int out_size, void* d_ws,
                              size_t ws_size, hipStream_t stream) {
  const float* q = (const float*)d_in[0];
  const float* k = (const float*)d_in[1];
  const float* v = (const float*)d_in[2];
  const float* wq = (const float*)d_in[3];
  const float* bq = (const float*)d_in[4];
  const float* wk = (const float*)d_in[5];
  const float* bk = (const float*)d_in[6];
  const float* wv = (const float*)d_in[7];
  const float* bv = (const float*)d_in[8];
  const float* wo = (const float*)d_in[9];
  const float* bo = (const float*)d_in[10];
  float* out = (float*)d_out;

  ushort* ws = (ushort*)d_ws;

  prep_all<<<dim3(320), 256, 0, stream>>>(wq, wk, wv, wo, ws);
  gemm_qkv<<<dim3(3072), 64, 0, stream>>>(q, k, v, ws, ws, bq, bk, bv);
  attn_out<<<dim3(kS / 32, 4), 512, 0, stream>>>(ws, bo, out);
}

// Round 8
// 147.344 us; speedup vs baseline: 1.0319x; 1.0319x over previous
//
#include <hip/hip_runtime.h>

typedef unsigned int uint;
typedef unsigned short ushort;
typedef __attribute__((ext_vector_type(8))) short bf16x8;
typedef __attribute__((ext_vector_type(4))) float f32x4;

namespace {
constexpr int kS = 2048;
constexpr int kD = 512;
constexpr int kH = 8;
constexpr int kBand = 16;

// Workspace offsets (ushort units).
constexpr size_t kQpk = 0;                    // 32 bh x 128 g x 2 kc x 512
constexpr size_t kKpk = 4194304;              // 32 bh x 130 g x 2 kc x 512
constexpr size_t kVpk = kKpk + 4259840;       // 32 bh x 65 gg x 4 nt x 512
constexpr size_t kApk = kVpk + 4259840;       // 3 x 8192 rows x 512
constexpr size_t kBpk = kApk + 12582912;      // 4 z x 8 c x 16 it x 2048
}  // namespace

static __device__ __forceinline__ ushort f2bf(float f) {
  uint u = __builtin_bit_cast(uint, f);
  u = (u + 0x7fffu + ((u >> 16) & 1u)) >> 16;  // RNE
  return (ushort)u;
}

// 8 fp32 -> bf16x8 via v_cvt_pk_bf16_f32 (RNE; bit-identical to f2bf).
static __device__ __forceinline__ bf16x8 cvt8(f32x4 lo, f32x4 hi) {
  uint4 r;
  asm("v_cvt_pk_bf16_f32 %0, %1, %2" : "=v"(r.x) : "v"(lo[0]), "v"(lo[1]));
  asm("v_cvt_pk_bf16_f32 %0, %1, %2" : "=v"(r.y) : "v"(lo[2]), "v"(lo[3]));
  asm("v_cvt_pk_bf16_f32 %0, %1, %2" : "=v"(r.z) : "v"(hi[0]), "v"(hi[1]));
  asm("v_cvt_pk_bf16_f32 %0, %1, %2" : "=v"(r.w) : "v"(hi[2]), "v"(hi[3]));
  return __builtin_bit_cast(bf16x8, r);
}

// ---------------------------------------------------------------------------
// prep_all: [0,768): q/k/v fp32 -> Apk bf16 packed. 2 blocks per 64-token
//           slab (8 K-chunks each) -> 12 waves/CU streaming TLP (was 6).
//           [768,1024): weights -> Bpk packed.
//           [1024,1088): zero-fill Vpk pad groups.
// ---------------------------------------------------------------------------
__global__ __launch_bounds__(256) void prep_all(
    const float* __restrict__ q, const float* __restrict__ k,
    const float* __restrict__ v, const float* __restrict__ wq,
    const float* __restrict__ wk, const float* __restrict__ wv,
    const float* __restrict__ wo, ushort* __restrict__ ws) {
  __shared__ float Ws[64][65];
  const int blk = blockIdx.x, tid = threadIdx.x;
  if (blk < 768) {  // ---- A packing (split: 8 chunks per block) ----
    const int z = blk >> 8, sub = blk & 255;
    const int rb = sub >> 1, half = sub & 1;
    const float* X = z == 0 ? q : (z == 1 ? k : v);
    ushort* A = ws + kApk + (size_t)z * 4194304 + (size_t)rb * 32768;
    const int tl = tid >> 2, dq = tid & 3;
    const float* src = X + (size_t)(rb * 64 + tl) * kD + dq * 8 + half * 256;
    ushort* dstb =
        A + (tl >> 4) * 512 + (dq * 16 + (tl & 15)) * 8 + half * 16384;
#pragma unroll
    for (int c = 0; c < 8; ++c) {
      const f32x4 lo = *(const f32x4*)(src + c * 32);
      const f32x4 hi = *(const f32x4*)(src + c * 32 + 4);
      *(bf16x8*)(dstb + c * 2048) = cvt8(lo, hi);
    }
    return;
  }
  if (blk >= 1024) {  // ---- Vpk pad zero-fill ----
    const int idx = blk - 1024;  // 0..63
    const int bh = idx >> 1, gg = (idx & 1) * 64;
    ushort* p = ws + kVpk + ((size_t)(bh * 65 + gg) * 4) * 512 + tid * 8;
    *(uint4*)p = (uint4){0, 0, 0, 0};
    return;
  }
  // ---- weight packing ----
  const int w = blk - 768;  // 0..255
  const int z = w >> 6;
  const float* W = z == 0 ? wq : (z == 1 ? wk : (z == 2 ? wv : wo));
  const int kt = ((w >> 3) & 7) * 64, nt = (w & 7) * 64;
  const int r = tid >> 2, c0 = (tid & 3) * 16;
#pragma unroll
  for (int i = 0; i < 4; ++i) {
    const float4 x =
        *(const float4*)(W + (size_t)(kt + r) * kD + nt + c0 + i * 4);
    Ws[r][c0 + i * 4 + 0] = x.x;
    Ws[r][c0 + i * 4 + 1] = x.y;
    Ws[r][c0 + i * 4 + 2] = x.z;
    Ws[r][c0 + i * 4 + 3] = x.w;
  }
  __syncthreads();
  const int nl = tid >> 2, k0 = (tid & 3) * 16;
  alignas(16) ushort tmp[16];
#pragma unroll
  for (int i = 0; i < 16; ++i) tmp[i] = f2bf(Ws[k0 + i][nl]);
  const int ng = nt + nl, kg = kt + k0;
  const int c = ng >> 6, sub = (ng >> 4) & 3, l = ng & 15;
  const int it = kg >> 5, q0 = (kg >> 3) & 3;  // q0 in {0,2}
  ushort* base = ws + kBpk + ((size_t)(z * 8 + c) * 16 + it) * 2048 +
                 (sub * 64 + l) * 8;
  *(uint4*)(base + q0 * 128) = *(const uint4*)&tmp[0];
  *(uint4*)(base + (q0 + 1) * 128) = *(const uint4*)&tmp[8];
}

// ---------------------------------------------------------------------------
// QKV GEMM, barrier-free fragment-packed (r6-verified, 149.1us config): one
// wave per 64x64 tile; all loads 1KB-contiguous dwordx4; 3 frag sets = 2-deep
// prefetch; no LDS in K-loop, no s_barrier. Epilogue packs Q/K/V for attn.
// ---------------------------------------------------------------------------
__global__ __launch_bounds__(64) void gemm_qkv(
    const ushort* __restrict__ ws_c, ushort* __restrict__ ws,
    const float* __restrict__ bq, const float* __restrict__ bk,
    const float* __restrict__ bv) {
  __shared__ alignas(16) ushort Tl[64 * 72];

  const int lane = threadIdx.x, l15 = lane & 15, qd = lane >> 4;
  const int lin = blockIdx.x;
  const int xcd = lin & 7, j = lin >> 3;
  const int ct = j & 7;
  const int rtl = xcd + 8 * (j >> 3);  // 0..383
  const int mode = rtl >> 7, rt = rtl & 127;
  const int row0 = rt * 64;

  const float* bias = mode == 0 ? bq : (mode == 1 ? bk : bv);
  const ushort* pa =
      ws_c + kApk + (size_t)mode * 4194304 + (size_t)rt * 32768 + lane * 8;
  const ushort* pb =
      ws_c + kBpk + ((size_t)(mode * 8 + ct) * 16) * 2048 + lane * 8;

  f32x4 acc[4][4];
#pragma unroll
  for (int mi = 0; mi < 4; ++mi)
#pragma unroll
    for (int ni = 0; ni < 4; ++ni) acc[mi][ni] = (f32x4)(0.f);

  bf16x8 Af[3][4], Bf[3][4];
#define LDSET(s, itv)                                                  \
  {                                                                    \
    _Pragma("unroll") for (int x = 0; x < 4; ++x) {                    \
      Af[s][x] = *(const bf16x8*)(pa + (itv)*2048 + x * 512);          \
      Bf[s][x] = *(const bf16x8*)(pb + (itv)*2048 + x * 512);          \
    }                                                                  \
  }
  LDSET(0, 0);
  LDSET(1, 1);
#pragma unroll
  for (int it = 0; it < 16; ++it) {
    if (it < 14) LDSET((it + 2) % 3, it + 2);
    const int s = it % 3;
#pragma unroll
    for (int mi = 0; mi < 4; ++mi)
#pragma unroll
      for (int ni = 0; ni < 4; ++ni)
        acc[mi][ni] = __builtin_amdgcn_mfma_f32_16x16x32_bf16(
            Af[s][mi], Bf[s][ni], acc[mi][ni], 0, 0, 0);
  }
#undef LDSET

  float bcol[4];
#pragma unroll
  for (int ni = 0; ni < 4; ++ni) bcol[ni] = bias[ct * 64 + ni * 16 + l15];

  const int bh = (row0 >> 11) * kH + ct;  // b*8 + h (head == col-tile)
  if (mode <= 1) {  // transpose to [token_local][dlocal], store packed Q/K
#pragma unroll
    for (int mi = 0; mi < 4; ++mi)
#pragma unroll
      for (int ni = 0; ni < 4; ++ni)
#pragma unroll
        for (int r = 0; r < 4; ++r)
          Tl[(mi * 16 + qd * 4 + r) * 72 + ni * 16 + l15] =
              f2bf(acc[mi][ni][r] + bcol[ni]);
    asm volatile("s_waitcnt lgkmcnt(0)" ::: "memory");
    const int s = (row0 & (kS - 1)) + lane;  // in-batch position
    const int g = s >> 4;
    const ushort* Trow = &Tl[lane * 72];
    ushort* base =
        (mode == 0)
            ? ws + kQpk + ((size_t)(bh * 128 + g) * 2) * 512 + (s & 15) * 8
            : ws + kKpk + ((size_t)(bh * 130 + g + 1) * 2) * 512 + (s & 15) * 8;
#pragma unroll
    for (int cc = 0; cc < 8; ++cc)
      *(uint4*)(base + (cc >> 2) * 512 + (cc & 3) * 128) =
          *(const uint4*)&Trow[cc * 8];
  } else {  // mode 2: transpose to [dlocal][token_local], store packed V
#pragma unroll
    for (int mi = 0; mi < 4; ++mi)
#pragma unroll
      for (int ni = 0; ni < 4; ++ni)
#pragma unroll
        for (int r = 0; r < 4; ++r)
          Tl[(ni * 16 + l15) * 72 + mi * 16 + qd * 4 + r] =
              f2bf(acc[mi][ni][r] + bcol[ni]);
    asm volatile("s_waitcnt lgkmcnt(0)" ::: "memory");
    const int nt = lane >> 4, l15v = lane & 15;
    const int sb = (row0 & (kS - 1)) + 16;
    const ushort* Trow = &Tl[lane * 72];
#pragma unroll
    for (int cc = 0; cc < 8; ++cc) {
      const int sc = sb + cc * 8;
      const int gg = sc >> 5, khc = (sc >> 3) & 3;
      ushort* dst = ws + kVpk + ((size_t)(bh * 65 + gg) * 4 + nt) * 512 +
                    khc * 128 + l15v * 8;
      *(uint4*)dst = *(const uint4*)&Trow[cc * 8];
    }
  }
}

// ---------------------------------------------------------------------------
// FUSED attention + out-projection (r6-verified). Block = 512 threads =
// 8 waves = 8 heads of one (b, 32-query tile). grid (64, 4).
// ---------------------------------------------------------------------------
__global__ __launch_bounds__(512) void attn_out(
    const ushort* __restrict__ ws_c, const float* __restrict__ bo,
    float* __restrict__ outp) {
  __shared__ alignas(16) ushort Pl[8 * 32 * 72];  // per-wave slices

  const int tid = threadIdx.x;
  const int w = tid >> 6, lane = tid & 63, l15 = lane & 15, qd = lane >> 4;
  const int b = blockIdx.y;
  const int q0 = blockIdx.x * 32;
  const int bh = b * kH + w;  // wave == head
  ushort* Plw = &Pl[w * 2304];

  const ushort* Qpk = ws_c + kQpk;
  const ushort* Kpk = ws_c + kKpk;
  const ushort* Vpk = ws_c + kVpk;

  // ---- attention phase ----
  bf16x8 qf[2][2], kf[4][2];
#pragma unroll
  for (int mi = 0; mi < 2; ++mi)
#pragma unroll
    for (int kc = 0; kc < 2; ++kc)
      qf[mi][kc] = *(const bf16x8*)&Qpk[((size_t)(bh * 128 + (q0 >> 4) + mi) *
                                            2 + kc) * 512 + lane * 8];
#pragma unroll
  for (int ni = 0; ni < 4; ++ni)
#pragma unroll
    for (int kc = 0; kc < 2; ++kc)
      kf[ni][kc] = *(const bf16x8*)&Kpk[((size_t)(bh * 130 + (q0 >> 4) + ni) *
                                            2 + kc) * 512 + lane * 8];

  f32x4 S[2][4];
#pragma unroll
  for (int mi = 0; mi < 2; ++mi)
#pragma unroll
    for (int ni = 0; ni < 4; ++ni) S[mi][ni] = (f32x4)(0.f);
#pragma unroll
  for (int mi = 0; mi < 2; ++mi)
#pragma unroll
    for (int ni = 0; ni < 4; ++ni)
#pragma unroll
      for (int kc = 0; kc < 2; ++kc)
        S[mi][ni] = __builtin_amdgcn_mfma_f32_16x16x32_bf16(
            qf[mi][kc], kf[ni][kc], S[mi][ni], 0, 0, 0);

#pragma unroll
  for (int mi = 0; mi < 2; ++mi)
#pragma unroll
    for (int ni = 0; ni < 4; ++ni)
#pragma unroll
      for (int r = 0; r < 4; ++r) {
        const int q_local = mi * 16 + qd * 4 + r;
        const int key_local = ni * 16 + l15;
        const int key = q0 - kBand + key_local;
        const int dlt = key_local - q_local;
        const bool ok = (dlt >= 0) && (dlt <= 32) && (key >= 0) && (key < kS);
        S[mi][ni][r] = ok ? S[mi][ni][r] * 0.125f : -3.0e38f;
      }

  float inv[2][4];
#pragma unroll
  for (int mi = 0; mi < 2; ++mi)
#pragma unroll
    for (int r = 0; r < 4; ++r) {
      float m = S[mi][0][r];
#pragma unroll
      for (int ni = 1; ni < 4; ++ni) m = fmaxf(m, S[mi][ni][r]);
      m = fmaxf(m, __shfl_xor(m, 1));
      m = fmaxf(m, __shfl_xor(m, 2));
      m = fmaxf(m, __shfl_xor(m, 4));
      m = fmaxf(m, __shfl_xor(m, 8));
      float s = 0.f;
#pragma unroll
      for (int ni = 0; ni < 4; ++ni) {
        const float e = __expf(S[mi][ni][r] - m);
        S[mi][ni][r] = e;
        s += e;
      }
      s += __shfl_xor(s, 1);
      s += __shfl_xor(s, 2);
      s += __shfl_xor(s, 4);
      s += __shfl_xor(s, 8);
      inv[mi][r] = 1.f / s;
    }

  // P -> own Pl slice (C-layout scatter, stride 72), read back in A-layout.
#pragma unroll
  for (int mi = 0; mi < 2; ++mi)
#pragma unroll
    for (int ni = 0; ni < 4; ++ni)
#pragma unroll
      for (int r = 0; r < 4; ++r)
        Plw[(mi * 16 + qd * 4 + r) * 72 + ni * 16 + l15] = f2bf(S[mi][ni][r]);
  asm volatile("s_waitcnt lgkmcnt(0)" ::: "memory");  // wave-local RAW

  f32x4 O[2][4];
#pragma unroll
  for (int mi = 0; mi < 2; ++mi)
#pragma unroll
    for (int nt = 0; nt < 4; ++nt) O[mi][nt] = (f32x4)(0.f);

#pragma unroll
  for (int kc = 0; kc < 2; ++kc) {
    bf16x8 pf[2], vfr[4];
#pragma unroll
    for (int mi = 0; mi < 2; ++mi)
      pf[mi] = *(const bf16x8*)&Plw[(mi * 16 + l15) * 72 + kc * 32 + qd * 8];
#pragma unroll
    for (int nt = 0; nt < 4; ++nt)
      vfr[nt] = *(const bf16x8*)&Vpk[((size_t)(bh * 65 + (q0 >> 5) + kc) * 4 +
                                       nt) * 512 + lane * 8];
#pragma unroll
    for (int mi = 0; mi < 2; ++mi)
#pragma unroll
      for (int nt = 0; nt < 4; ++nt)
        O[mi][nt] = __builtin_amdgcn_mfma_f32_16x16x32_bf16(pf[mi], vfr[nt],
                                                            O[mi][nt], 0, 0, 0);
  }

  // O (scaled) -> own Pl slice as [token_local][d_local], stride 72.
#pragma unroll
  for (int mi = 0; mi < 2; ++mi)
#pragma unroll
    for (int nt = 0; nt < 4; ++nt)
#pragma unroll
      for (int r = 0; r < 4; ++r)
        Plw[(mi * 16 + qd * 4 + r) * 72 + nt * 16 + l15] =
            f2bf(O[mi][nt][r] * inv[mi][r]);

  __syncthreads();  // all 8 heads' O visible to all waves

  // ---- out-projection phase: wave w computes cols [w*64, w*64+64) ----
  const ushort* pb =
      ws_c + kBpk + ((size_t)(3 * 8 + w) * 16) * 2048 + lane * 8;

  f32x4 acc[2][4];
#pragma unroll
  for (int mi = 0; mi < 2; ++mi)
#pragma unroll
    for (int ni = 0; ni < 4; ++ni) acc[mi][ni] = (f32x4)(0.f);

  bf16x8 Bf[2][4];
#pragma unroll
  for (int x = 0; x < 4; ++x) Bf[0][x] = *(const bf16x8*)(pb + x * 512);
#pragma unroll
  for (int it = 0; it < 16; ++it) {
    if (it < 15) {
#pragma unroll
      for (int x = 0; x < 4; ++x)
        Bf[(it + 1) & 1][x] =
            *(const bf16x8*)(pb + (size_t)(it + 1) * 2048 + x * 512);
    }
    bf16x8 af[2];
#pragma unroll
    for (int mi = 0; mi < 2; ++mi)
      af[mi] = *(const bf16x8*)&Pl[(it >> 1) * 2304 + (mi * 16 + l15) * 72 +
                                   (it & 1) * 32 + qd * 8];
#pragma unroll
    for (int mi = 0; mi < 2; ++mi)
#pragma unroll
      for (int ni = 0; ni < 4; ++ni)
        acc[mi][ni] = __builtin_amdgcn_mfma_f32_16x16x32_bf16(
            af[mi], Bf[it & 1][ni], acc[mi][ni], 0, 0, 0);
  }

#pragma unroll
  for (int ni = 0; ni < 4; ++ni) {
    const int colg = w * 64 + ni * 16 + l15;
    const float bc = bo[colg];
#pragma unroll
    for (int mi = 0; mi < 2; ++mi)
#pragma unroll
      for (int r = 0; r < 4; ++r) {
        const int token = b * kS + q0 + mi * 16 + qd * 4 + r;
        outp[(size_t)token * kD + colg] = acc[mi][ni][r] + bc;
      }
  }
}

extern "C" void kernel_launch(void* const* d_in, const int* in_sizes, int n_in,
                              void* d_out, int out_size, void* d_ws,
                              size_t ws_size, hipStream_t stream) {
  const float* q = (const float*)d_in[0];
  const float* k = (const float*)d_in[1];
  const float* v = (const float*)d_in[2];
  const float* wq = (const float*)d_in[3];
  const float* bq = (const float*)d_in[4];
  const float* wk = (const float*)d_in[5];
  const float* bk = (const float*)d_in[6];
  const float* wv = (const float*)d_in[7];
  const float* bv = (const float*)d_in[8];
  const float* wo = (const float*)d_in[9];
  const float* bo = (const float*)d_in[10];
  float* out = (float*)d_out;

  ushort* ws = (ushort*)d_ws;

  prep_all<<<dim3(1088), 256, 0, stream>>>(q, k, v, wq, wk, wv, wo, ws);
  gemm_qkv<<<dim3(3072), 64, 0, stream>>>(ws, ws, bq, bk, bv);
  attn_out<<<dim3(kS / 32, 4), 512, 0, stream>>>(ws, bo, out);
}

// Round 9
// 145.166 us; speedup vs baseline: 1.0474x; 1.0150x over previous
//
#include <hip/hip_runtime.h>

typedef unsigned int uint;
typedef unsigned short ushort;
typedef __attribute__((ext_vector_type(8))) short bf16x8;
typedef __attribute__((ext_vector_type(4))) float f32x4;

namespace {
constexpr int kS = 2048;
constexpr int kD = 512;
constexpr int kH = 8;
constexpr int kBand = 16;

// Workspace offsets (ushort units).
constexpr size_t kQpk = 0;                    // 32 bh x 128 g x 2 kc x 512
constexpr size_t kKpk = 4194304;              // 32 bh x 130 g x 2 kc x 512
constexpr size_t kVpk = kKpk + 4259840;       // 32 bh x 65 gg x 4 nt x 512
constexpr size_t kApk = kVpk + 4259840;       // 3 x 8192 rows x 512
constexpr size_t kBpk = kApk + 12582912;      // 4 z x 8 c x 16 it x 2048
}  // namespace

static __device__ __forceinline__ ushort f2bf(float f) {
  uint u = __builtin_bit_cast(uint, f);
  u = (u + 0x7fffu + ((u >> 16) & 1u)) >> 16;  // RNE
  return (ushort)u;
}

// 8 fp32 -> bf16x8 via v_cvt_pk_bf16_f32 (RNE; bit-identical to f2bf).
static __device__ __forceinline__ bf16x8 cvt8(f32x4 lo, f32x4 hi) {
  uint4 r;
  asm("v_cvt_pk_bf16_f32 %0, %1, %2" : "=v"(r.x) : "v"(lo[0]), "v"(lo[1]));
  asm("v_cvt_pk_bf16_f32 %0, %1, %2" : "=v"(r.y) : "v"(lo[2]), "v"(lo[3]));
  asm("v_cvt_pk_bf16_f32 %0, %1, %2" : "=v"(r.z) : "v"(hi[0]), "v"(hi[1]));
  asm("v_cvt_pk_bf16_f32 %0, %1, %2" : "=v"(r.w) : "v"(hi[2]), "v"(hi[3]));
  return __builtin_bit_cast(bf16x8, r);
}

// ---------------------------------------------------------------------------
// prep_all: [0,768): q/k/v fp32 -> Apk bf16 packed (r8-verified split form).
//           [768,1024): weights -> Bpk packed.
//           [1024,1088): zero-fill Vpk pad groups.
// ---------------------------------------------------------------------------
__global__ __launch_bounds__(256) void prep_all(
    const float* __restrict__ q, const float* __restrict__ k,
    const float* __restrict__ v, const float* __restrict__ wq,
    const float* __restrict__ wk, const float* __restrict__ wv,
    const float* __restrict__ wo, ushort* __restrict__ ws) {
  __shared__ float Ws[64][65];
  const int blk = blockIdx.x, tid = threadIdx.x;
  if (blk < 768) {  // ---- A packing (split: 8 chunks per block) ----
    const int z = blk >> 8, sub = blk & 255;
    const int rb = sub >> 1, half = sub & 1;
    const float* X = z == 0 ? q : (z == 1 ? k : v);
    ushort* A = ws + kApk + (size_t)z * 4194304 + (size_t)rb * 32768;
    const int tl = tid >> 2, dq = tid & 3;
    const float* src = X + (size_t)(rb * 64 + tl) * kD + dq * 8 + half * 256;
    ushort* dstb =
        A + (tl >> 4) * 512 + (dq * 16 + (tl & 15)) * 8 + half * 16384;
#pragma unroll
    for (int c = 0; c < 8; ++c) {
      const f32x4 lo = *(const f32x4*)(src + c * 32);
      const f32x4 hi = *(const f32x4*)(src + c * 32 + 4);
      *(bf16x8*)(dstb + c * 2048) = cvt8(lo, hi);
    }
    return;
  }
  if (blk >= 1024) {  // ---- Vpk pad zero-fill ----
    const int idx = blk - 1024;  // 0..63
    const int bh = idx >> 1, gg = (idx & 1) * 64;
    ushort* p = ws + kVpk + ((size_t)(bh * 65 + gg) * 4) * 512 + tid * 8;
    *(uint4*)p = (uint4){0, 0, 0, 0};
    return;
  }
  // ---- weight packing ----
  const int w = blk - 768;  // 0..255
  const int z = w >> 6;
  const float* W = z == 0 ? wq : (z == 1 ? wk : (z == 2 ? wv : wo));
  const int kt = ((w >> 3) & 7) * 64, nt = (w & 7) * 64;
  const int r = tid >> 2, c0 = (tid & 3) * 16;
#pragma unroll
  for (int i = 0; i < 4; ++i) {
    const float4 x =
        *(const float4*)(W + (size_t)(kt + r) * kD + nt + c0 + i * 4);
    Ws[r][c0 + i * 4 + 0] = x.x;
    Ws[r][c0 + i * 4 + 1] = x.y;
    Ws[r][c0 + i * 4 + 2] = x.z;
    Ws[r][c0 + i * 4 + 3] = x.w;
  }
  __syncthreads();
  const int nl = tid >> 2, k0 = (tid & 3) * 16;
  alignas(16) ushort tmp[16];
#pragma unroll
  for (int i = 0; i < 16; ++i) tmp[i] = f2bf(Ws[k0 + i][nl]);
  const int ng = nt + nl, kg = kt + k0;
  const int c = ng >> 6, sub = (ng >> 4) & 3, l = ng & 15;
  const int it = kg >> 5, q0 = (kg >> 3) & 3;  // q0 in {0,2}
  ushort* base = ws + kBpk + ((size_t)(z * 8 + c) * 16 + it) * 2048 +
                 (sub * 64 + l) * 8;
  *(uint4*)(base + q0 * 128) = *(const uint4*)&tmp[0];
  *(uint4*)(base + (q0 + 1) * 128) = *(const uint4*)&tmp[8];
}

// ---------------------------------------------------------------------------
// QKV GEMM, barrier-free fragment-packed with wave co-location for A reuse:
// block = 256 threads = 4 waves = 4 col-tiles of ONE 64-row tile. The 4
// waves issue IDENTICAL A-fragment addresses each iteration -> waves 1-3 hit
// L1 (A L2 traffic /4). No barriers, no LDS sharing in the K-loop; each wave
// is the r6/r8-verified independent program. grid 768 = 3 blocks/CU (even).
// ---------------------------------------------------------------------------
__global__ __launch_bounds__(256) void gemm_qkv(
    const ushort* __restrict__ ws_c, ushort* __restrict__ ws,
    const float* __restrict__ bq, const float* __restrict__ bk,
    const float* __restrict__ bv) {
  __shared__ alignas(16) ushort Tl[4 * 64 * 72];  // per-wave epilogue slices

  const int tid = threadIdx.x;
  const int w4 = tid >> 6, lane = tid & 63, l15 = lane & 15, qd = lane >> 4;
  const int lin = blockIdx.x;
  const int xcd = lin & 7, j = lin >> 3;       // j 0..95
  const int cg = j & 1;                        // col group (0: ct 0-3, 1: 4-7)
  const int rtl = xcd + 8 * (j >> 1);          // 0..383
  const int mode = rtl >> 7, rt = rtl & 127;
  const int row0 = rt * 64;
  const int ct = cg * 4 + w4;                  // this wave's col-tile 0..7

  const float* bias = mode == 0 ? bq : (mode == 1 ? bk : bv);
  const ushort* pa =
      ws_c + kApk + (size_t)mode * 4194304 + (size_t)rt * 32768 + lane * 8;
  const ushort* pb =
      ws_c + kBpk + ((size_t)(mode * 8 + ct) * 16) * 2048 + lane * 8;

  f32x4 acc[4][4];
#pragma unroll
  for (int mi = 0; mi < 4; ++mi)
#pragma unroll
    for (int ni = 0; ni < 4; ++ni) acc[mi][ni] = (f32x4)(0.f);

  bf16x8 Af[3][4], Bf[3][4];
#define LDSET(s, itv)                                                  \
  {                                                                    \
    _Pragma("unroll") for (int x = 0; x < 4; ++x) {                    \
      Af[s][x] = *(const bf16x8*)(pa + (itv)*2048 + x * 512);          \
      Bf[s][x] = *(const bf16x8*)(pb + (itv)*2048 + x * 512);          \
    }                                                                  \
  }
  LDSET(0, 0);
  LDSET(1, 1);
#pragma unroll
  for (int it = 0; it < 16; ++it) {
    if (it < 14) LDSET((it + 2) % 3, it + 2);
    const int s = it % 3;
#pragma unroll
    for (int mi = 0; mi < 4; ++mi)
#pragma unroll
      for (int ni = 0; ni < 4; ++ni)
        acc[mi][ni] = __builtin_amdgcn_mfma_f32_16x16x32_bf16(
            Af[s][mi], Bf[s][ni], acc[mi][ni], 0, 0, 0);
  }
#undef LDSET

  float bcol[4];
#pragma unroll
  for (int ni = 0; ni < 4; ++ni) bcol[ni] = bias[ct * 64 + ni * 16 + l15];

  ushort* Tw = &Tl[w4 * 4608];  // wave-private 64x72 slice
  const int bh = (row0 >> 11) * kH + ct;  // b*8 + h (head == col-tile)
  if (mode <= 1) {  // transpose to [token_local][dlocal], store packed Q/K
#pragma unroll
    for (int mi = 0; mi < 4; ++mi)
#pragma unroll
      for (int ni = 0; ni < 4; ++ni)
#pragma unroll
        for (int r = 0; r < 4; ++r)
          Tw[(mi * 16 + qd * 4 + r) * 72 + ni * 16 + l15] =
              f2bf(acc[mi][ni][r] + bcol[ni]);
    asm volatile("s_waitcnt lgkmcnt(0)" ::: "memory");  // wave-local RAW
    const int s = (row0 & (kS - 1)) + lane;  // in-batch position
    const int g = s >> 4;
    const ushort* Trow = &Tw[lane * 72];
    ushort* base =
        (mode == 0)
            ? ws + kQpk + ((size_t)(bh * 128 + g) * 2) * 512 + (s & 15) * 8
            : ws + kKpk + ((size_t)(bh * 130 + g + 1) * 2) * 512 + (s & 15) * 8;
#pragma unroll
    for (int cc = 0; cc < 8; ++cc)
      *(uint4*)(base + (cc >> 2) * 512 + (cc & 3) * 128) =
          *(const uint4*)&Trow[cc * 8];
  } else {  // mode 2: transpose to [dlocal][token_local], store packed V
#pragma unroll
    for (int mi = 0; mi < 4; ++mi)
#pragma unroll
      for (int ni = 0; ni < 4; ++ni)
#pragma unroll
        for (int r = 0; r < 4; ++r)
          Tw[(ni * 16 + l15) * 72 + mi * 16 + qd * 4 + r] =
              f2bf(acc[mi][ni][r] + bcol[ni]);
    asm volatile("s_waitcnt lgkmcnt(0)" ::: "memory");
    const int nt = lane >> 4, l15v = lane & 15;
    const int sb = (row0 & (kS - 1)) + 16;
    const ushort* Trow = &Tw[lane * 72];
#pragma unroll
    for (int cc = 0; cc < 8; ++cc) {
      const int sc = sb + cc * 8;
      const int gg = sc >> 5, khc = (sc >> 3) & 3;
      ushort* dst = ws + kVpk + ((size_t)(bh * 65 + gg) * 4 + nt) * 512 +
                    khc * 128 + l15v * 8;
      *(uint4*)dst = *(const uint4*)&Trow[cc * 8];
    }
  }
}

// ---------------------------------------------------------------------------
// FUSED attention + out-projection (r6/r8-verified). Block = 512 threads =
// 8 waves = 8 heads of one (b, 32-query tile). grid (64, 4).
// ---------------------------------------------------------------------------
__global__ __launch_bounds__(512) void attn_out(
    const ushort* __restrict__ ws_c, const float* __restrict__ bo,
    float* __restrict__ outp) {
  __shared__ alignas(16) ushort Pl[8 * 32 * 72];  // per-wave slices

  const int tid = threadIdx.x;
  const int w = tid >> 6, lane = tid & 63, l15 = lane & 15, qd = lane >> 4;
  const int b = blockIdx.y;
  const int q0 = blockIdx.x * 32;
  const int bh = b * kH + w;  // wave == head
  ushort* Plw = &Pl[w * 2304];

  const ushort* Qpk = ws_c + kQpk;
  const ushort* Kpk = ws_c + kKpk;
  const ushort* Vpk = ws_c + kVpk;

  // ---- attention phase ----
  bf16x8 qf[2][2], kf[4][2];
#pragma unroll
  for (int mi = 0; mi < 2; ++mi)
#pragma unroll
    for (int kc = 0; kc < 2; ++kc)
      qf[mi][kc] = *(const bf16x8*)&Qpk[((size_t)(bh * 128 + (q0 >> 4) + mi) *
                                            2 + kc) * 512 + lane * 8];
#pragma unroll
  for (int ni = 0; ni < 4; ++ni)
#pragma unroll
    for (int kc = 0; kc < 2; ++kc)
      kf[ni][kc] = *(const bf16x8*)&Kpk[((size_t)(bh * 130 + (q0 >> 4) + ni) *
                                            2 + kc) * 512 + lane * 8];

  f32x4 S[2][4];
#pragma unroll
  for (int mi = 0; mi < 2; ++mi)
#pragma unroll
    for (int ni = 0; ni < 4; ++ni) S[mi][ni] = (f32x4)(0.f);
#pragma unroll
  for (int mi = 0; mi < 2; ++mi)
#pragma unroll
    for (int ni = 0; ni < 4; ++ni)
#pragma unroll
      for (int kc = 0; kc < 2; ++kc)
        S[mi][ni] = __builtin_amdgcn_mfma_f32_16x16x32_bf16(
            qf[mi][kc], kf[ni][kc], S[mi][ni], 0, 0, 0);

#pragma unroll
  for (int mi = 0; mi < 2; ++mi)
#pragma unroll
    for (int ni = 0; ni < 4; ++ni)
#pragma unroll
      for (int r = 0; r < 4; ++r) {
        const int q_local = mi * 16 + qd * 4 + r;
        const int key_local = ni * 16 + l15;
        const int key = q0 - kBand + key_local;
        const int dlt = key_local - q_local;
        const bool ok = (dlt >= 0) && (dlt <= 32) && (key >= 0) && (key < kS);
        S[mi][ni][r] = ok ? S[mi][ni][r] * 0.125f : -3.0e38f;
      }

  float inv[2][4];
#pragma unroll
  for (int mi = 0; mi < 2; ++mi)
#pragma unroll
    for (int r = 0; r < 4; ++r) {
      float m = S[mi][0][r];
#pragma unroll
      for (int ni = 1; ni < 4; ++ni) m = fmaxf(m, S[mi][ni][r]);
      m = fmaxf(m, __shfl_xor(m, 1));
      m = fmaxf(m, __shfl_xor(m, 2));
      m = fmaxf(m, __shfl_xor(m, 4));
      m = fmaxf(m, __shfl_xor(m, 8));
      float s = 0.f;
#pragma unroll
      for (int ni = 0; ni < 4; ++ni) {
        const float e = __expf(S[mi][ni][r] - m);
        S[mi][ni][r] = e;
        s += e;
      }
      s += __shfl_xor(s, 1);
      s += __shfl_xor(s, 2);
      s += __shfl_xor(s, 4);
      s += __shfl_xor(s, 8);
      inv[mi][r] = 1.f / s;
    }

  // P -> own Pl slice (C-layout scatter, stride 72), read back in A-layout.
#pragma unroll
  for (int mi = 0; mi < 2; ++mi)
#pragma unroll
    for (int ni = 0; ni < 4; ++ni)
#pragma unroll
      for (int r = 0; r < 4; ++r)
        Plw[(mi * 16 + qd * 4 + r) * 72 + ni * 16 + l15] = f2bf(S[mi][ni][r]);
  asm volatile("s_waitcnt lgkmcnt(0)" ::: "memory");  // wave-local RAW

  f32x4 O[2][4];
#pragma unroll
  for (int mi = 0; mi < 2; ++mi)
#pragma unroll
    for (int nt = 0; nt < 4; ++nt) O[mi][nt] = (f32x4)(0.f);

#pragma unroll
  for (int kc = 0; kc < 2; ++kc) {
    bf16x8 pf[2], vfr[4];
#pragma unroll
    for (int mi = 0; mi < 2; ++mi)
      pf[mi] = *(const bf16x8*)&Plw[(mi * 16 + l15) * 72 + kc * 32 + qd * 8];
#pragma unroll
    for (int nt = 0; nt < 4; ++nt)
      vfr[nt] = *(const bf16x8*)&Vpk[((size_t)(bh * 65 + (q0 >> 5) + kc) * 4 +
                                       nt) * 512 + lane * 8];
#pragma unroll
    for (int mi = 0; mi < 2; ++mi)
#pragma unroll
      for (int nt = 0; nt < 4; ++nt)
        O[mi][nt] = __builtin_amdgcn_mfma_f32_16x16x32_bf16(pf[mi], vfr[nt],
                                                            O[mi][nt], 0, 0, 0);
  }

  // O (scaled) -> own Pl slice as [token_local][d_local], stride 72.
#pragma unroll
  for (int mi = 0; mi < 2; ++mi)
#pragma unroll
    for (int nt = 0; nt < 4; ++nt)
#pragma unroll
      for (int r = 0; r < 4; ++r)
        Plw[(mi * 16 + qd * 4 + r) * 72 + nt * 16 + l15] =
            f2bf(O[mi][nt][r] * inv[mi][r]);

  __syncthreads();  // all 8 heads' O visible to all waves

  // ---- out-projection phase: wave w computes cols [w*64, w*64+64) ----
  const ushort* pb =
      ws_c + kBpk + ((size_t)(3 * 8 + w) * 16) * 2048 + lane * 8;

  f32x4 acc[2][4];
#pragma unroll
  for (int mi = 0; mi < 2; ++mi)
#pragma unroll
    for (int ni = 0; ni < 4; ++ni) acc[mi][ni] = (f32x4)(0.f);

  bf16x8 Bf[2][4];
#pragma unroll
  for (int x = 0; x < 4; ++x) Bf[0][x] = *(const bf16x8*)(pb + x * 512);
#pragma unroll
  for (int it = 0; it < 16; ++it) {
    if (it < 15) {
#pragma unroll
      for (int x = 0; x < 4; ++x)
        Bf[(it + 1) & 1][x] =
            *(const bf16x8*)(pb + (size_t)(it + 1) * 2048 + x * 512);
    }
    bf16x8 af[2];
#pragma unroll
    for (int mi = 0; mi < 2; ++mi)
      af[mi] = *(const bf16x8*)&Pl[(it >> 1) * 2304 + (mi * 16 + l15) * 72 +
                                   (it & 1) * 32 + qd * 8];
#pragma unroll
    for (int mi = 0; mi < 2; ++mi)
#pragma unroll
      for (int ni = 0; ni < 4; ++ni)
        acc[mi][ni] = __builtin_amdgcn_mfma_f32_16x16x32_bf16(
            af[mi], Bf[it & 1][ni], acc[mi][ni], 0, 0, 0);
  }

#pragma unroll
  for (int ni = 0; ni < 4; ++ni) {
    const int colg = w * 64 + ni * 16 + l15;
    const float bc = bo[colg];
#pragma unroll
    for (int mi = 0; mi < 2; ++mi)
#pragma unroll
      for (int r = 0; r < 4; ++r) {
        const int token = b * kS + q0 + mi * 16 + qd * 4 + r;
        outp[(size_t)token * kD + colg] = acc[mi][ni][r] + bc;
      }
  }
}

extern "C" void kernel_launch(void* const* d_in, const int* in_sizes, int n_in,
                              void* d_out, int out_size, void* d_ws,
                              size_t ws_size, hipStream_t stream) {
  const float* q = (const float*)d_in[0];
  const float* k = (const float*)d_in[1];
  const float* v = (const float*)d_in[2];
  const float* wq = (const float*)d_in[3];
  const float* bq = (const float*)d_in[4];
  const float* wk = (const float*)d_in[5];
  const float* bk = (const float*)d_in[6];
  const float* wv = (const float*)d_in[7];
  const float* bv = (const float*)d_in[8];
  const float* wo = (const float*)d_in[9];
  const float* bo = (const float*)d_in[10];
  float* out = (float*)d_out;

  ushort* ws = (ushort*)d_ws;

  prep_all<<<dim3(1088), 256, 0, stream>>>(q, k, v, wq, wk, wv, wo, ws);
  gemm_qkv<<<dim3(768), 256, 0, stream>>>(ws, ws, bq, bk, bv);
  attn_out<<<dim3(kS / 32, 4), 512, 0, stream>>>(ws, bo, out);
}